// Round 1
// baseline (118.381 us; speedup 1.0000x reference)
//
#include <hip/hip_runtime.h>

// ---------------------------------------------------------------------------
// QuantumNeuralNetwork: the whole reference is affine in x.
//   out = x @ Mtot + btot
//   Mtot = in_W @ L @ meas_ops @ out_W,  btot = in_b @ L @ meas_ops @ out_W + out_b
// L (middle map: entangle + superposition + 3 circuit layers) is applied
// directly to the rows of in_W / in_b (it is linear along the hidden dim).
// ---------------------------------------------------------------------------

typedef float  fvec4  __attribute__((ext_vector_type(4)));
typedef float  f32x4  __attribute__((ext_vector_type(4)));
typedef short  short8 __attribute__((ext_vector_type(8)));
typedef unsigned short usvec4 __attribute__((ext_vector_type(4)));

#define H 512
#define NPAIR 4
#define PS 128
#define NL 3

__device__ __forceinline__ unsigned short f2bf(float f) {
    unsigned int u = __float_as_uint(f);
    unsigned int r = (u + 0x7fffu + ((u >> 16) & 1u)) >> 16;   // RNE
    return (unsigned short)r;
}

// w[h] = sum_s coeffs[s] * supW[s][h]
__global__ void k_w(const float* __restrict__ coeffs, const float* __restrict__ supW,
                    float* __restrict__ w) {
    int h = blockIdx.x * blockDim.x + threadIdx.x;
    if (h >= H) return;
    float acc = 0.f;
#pragma unroll
    for (int s = 0; s < 8; ++s) acc += coeffs[s] * supW[s * H + h];
    w[h] = acc;
}

// Entanglement applied to rows of Min (grid.x = R rows, grid.y = 4 pairs).
// out[r, p*128+j] = strength[p] * sum_i Min[r, p*128+i] * entW[p, i, jsrc(j)]
// jsrc swaps positions 2<->3 within each quad (CNOT column permutation).
__global__ void k_entangle(const float* __restrict__ Min, const float* __restrict__ entW,
                           const float* __restrict__ strength, float* __restrict__ Mout) {
    __shared__ float seg[PS];
    int r = blockIdx.x, p = blockIdx.y;
    int j = threadIdx.x;
    seg[j] = Min[r * H + p * PS + j];
    __syncthreads();
    int jsrc = (j & 2) ? (j ^ 1) : j;
    const float* wcol = entW + p * PS * PS + jsrc;
    float acc = 0.f;
#pragma unroll 8
    for (int i = 0; i < PS; ++i) acc += seg[i] * wcol[i * PS];
    Mout[r * H + p * PS + j] = acc * strength[p];
}

// Superposition (Hadamard + w scale) and 3 variational layers; all gates are
// quad-local and px/pz constant within a quad. One thread = one quad of one row.
__global__ void k_quadops(float* __restrict__ Mio, const float* __restrict__ w,
                          const float* __restrict__ cp, int R) {
    int idx = blockIdx.x * blockDim.x + threadIdx.x;
    if (idx >= R * (H / 4)) return;
    int r = idx >> 7, q = idx & 127;
    int c0 = q * 4;
    fvec4 v = *reinterpret_cast<const fvec4*>(Mio + r * H + c0);
    const float is2 = 0.70710678118654752440f;
    float t0, t1, t2, t3;
    // superposition: Hadamard pairs, then * w
    t0 = (v.x + v.y) * is2; t1 = (v.x - v.y) * is2;
    t2 = (v.z + v.w) * is2; t3 = (v.z - v.w) * is2;
    v.x = t0 * w[c0]; v.y = t1 * w[c0 + 1]; v.z = t2 * w[c0 + 2]; v.w = t3 * w[c0 + 3];
    int qb = c0 >> 6;  // qubit index (64 cols per qubit; quad never straddles)
#pragma unroll
    for (int l = 0; l < NL; ++l) {
        float px = cp[l * 24 + qb * 3 + 0];
        float pz = cp[l * 24 + qb * 3 + 2];
        // Hadamard
        t0 = (v.x + v.y) * is2; t1 = (v.x - v.y) * is2;
        t2 = (v.z + v.w) * is2; t3 = (v.z - v.w) * is2;
        v.x = t0; v.y = t1; v.z = t2; v.w = t3;
        // x += px * swap(x)
        t0 = v.x + px * v.y; t1 = v.y + px * v.x;
        t2 = v.z + px * v.w; t3 = v.w + px * v.z;
        v.x = t0; v.y = t1; v.z = t2; v.w = t3;
        // x += pz * PZ(x)
        v.x *= (1.f + pz); v.y *= (1.f - pz);
        v.z *= (1.f + pz); v.w *= (1.f - pz);
        // CNOT: swap quad positions 2,3
        t0 = v.z; v.z = v.w; v.w = t0;
    }
    *reinterpret_cast<fvec4*>(Mio + r * H + c0) = v;
}

// Transposing f32 -> bf16 convert: D[n][k] = bf16(S[k][n]); S,D are 512x512.
__global__ void k_convT(const float* __restrict__ S, unsigned short* __restrict__ D) {
    __shared__ float t[64][65];
    int tx = threadIdx.x & 63, ty = threadIdx.x >> 6;  // 64 x 4
    int k0 = blockIdx.x * 64, n0 = blockIdx.y * 64;
#pragma unroll
    for (int i = 0; i < 64; i += 4) t[i + ty][tx] = S[(k0 + i + ty) * H + n0 + tx];
    __syncthreads();
#pragma unroll
    for (int i = 0; i < 64; i += 4) D[(n0 + i + ty) * H + k0 + tx] = f2bf(t[tx][i + ty]);
}

// btot[o] = sum_h bmid[h] * M2[h][o] + outb[o]
__global__ void k_bias(const float* __restrict__ bmid, const float* __restrict__ M2,
                       const float* __restrict__ outb, float* __restrict__ btot) {
    int o = blockIdx.x * blockDim.x + threadIdx.x;
    if (o >= H) return;
    float acc = outb[o];
    for (int h = 0; h < H; ++h) acc += bmid[h] * M2[h * H + o];
    btot[o] = acc;
}

// C[M x 512] = A[M x 512] @ B[512 x 512] (+ bias), B given as Bt[n][k] bf16.
// bf16 MFMA 16x16x32, 128x128 tile, BK=32, 4 waves (2x2), each wave 64x64.
#define BM 128
#define BN 128
#define BK 32
#define LDT 56  // padded LDS row stride in bf16 elems (112 B: 16B-aligned, ~2-way banks)

__global__ __launch_bounds__(256) void k_gemm(const float* __restrict__ A,
                                              const unsigned short* __restrict__ Bt,
                                              float* __restrict__ C,
                                              const float* __restrict__ bias) {
    __shared__ unsigned short As[BM * LDT];
    __shared__ unsigned short Bs[BN * LDT];
    const int tid = threadIdx.x;
    const int bm = blockIdx.x * BM;
    const int bn = blockIdx.y * BN;
    const int lane = tid & 63;
    const int wid = tid >> 6;
    const int wm = wid >> 1, wn = wid & 1;

    f32x4 acc[4][4];
#pragma unroll
    for (int i = 0; i < 4; ++i)
#pragma unroll
        for (int j = 0; j < 4; ++j) acc[i][j] = (f32x4)0.f;

    const int ro = lane & 15;
    const int ko = (lane >> 4) * 8;

    for (int kt = 0; kt < H; kt += BK) {
        __syncthreads();
        // stage A: 128 rows x 32 f32 -> bf16
#pragma unroll
        for (int i = 0; i < 4; ++i) {
            int idx = i * 256 + tid;            // 0..1023 over (row, quad-of-4)
            int r = idx >> 3, q = idx & 7;
            fvec4 v = *reinterpret_cast<const fvec4*>(A + (size_t)(bm + r) * H + kt + q * 4);
            usvec4 hv;
            hv.x = f2bf(v.x); hv.y = f2bf(v.y); hv.z = f2bf(v.z); hv.w = f2bf(v.w);
            *reinterpret_cast<usvec4*>(&As[r * LDT + q * 4]) = hv;
        }
        // stage Bt: 128 n-rows x 32 k bf16
#pragma unroll
        for (int i = 0; i < 2; ++i) {
            int idx = i * 256 + tid;            // 0..511 over (n, chunk-of-8)
            int n = idx >> 2, c = idx & 3;
            short8 v = *reinterpret_cast<const short8*>(Bt + (size_t)(bn + n) * H + kt + c * 8);
            *reinterpret_cast<short8*>(&Bs[n * LDT + c * 8]) = v;
        }
        __syncthreads();

        short8 af[4], bf[4];
#pragma unroll
        for (int am = 0; am < 4; ++am)
            af[am] = *reinterpret_cast<const short8*>(&As[(wm * 64 + am * 16 + ro) * LDT + ko]);
#pragma unroll
        for (int bj = 0; bj < 4; ++bj)
            bf[bj] = *reinterpret_cast<const short8*>(&Bs[(wn * 64 + bj * 16 + ro) * LDT + ko]);
#pragma unroll
        for (int am = 0; am < 4; ++am)
#pragma unroll
            for (int bj = 0; bj < 4; ++bj)
                acc[am][bj] = __builtin_amdgcn_mfma_f32_16x16x32_bf16(af[am], bf[bj], acc[am][bj], 0, 0, 0);
    }

    // epilogue: D mapping col=lane&15, row=(lane>>4)*4+reg
    const int crow = (lane >> 4) * 4;
    const int ccol = lane & 15;
#pragma unroll
    for (int am = 0; am < 4; ++am) {
#pragma unroll
        for (int bj = 0; bj < 4; ++bj) {
            int gcol = bn + wn * 64 + bj * 16 + ccol;
            float bv = bias ? bias[gcol] : 0.f;
#pragma unroll
            for (int j = 0; j < 4; ++j) {
                int grow = bm + wm * 64 + am * 16 + crow + j;
                C[(size_t)grow * H + gcol] = acc[am][bj][j] + bv;
            }
        }
    }
}

extern "C" void kernel_launch(void* const* d_in, const int* in_sizes, int n_in,
                              void* d_out, int out_size, void* d_ws, size_t ws_size,
                              hipStream_t stream) {
    const float* x      = (const float*)d_in[0];   // (8,2048,512)
    const float* in_W   = (const float*)d_in[1];   // (512,512)
    const float* in_b   = (const float*)d_in[2];   // (512,)
    const float* ent_W  = (const float*)d_in[3];   // (4,128,128)
    const float* ent_s  = (const float*)d_in[4];   // (4,)
    const float* sup_W  = (const float*)d_in[5];   // (8,512)
    const float* sup_c  = (const float*)d_in[6];   // (8,)
    const float* cp     = (const float*)d_in[7];   // (3,8,3)
    const float* meas   = (const float*)d_in[8];   // (512,512)
    const float* out_W  = (const float*)d_in[9];   // (512,512)
    const float* out_b  = (const float*)d_in[10];  // (512,)
    float* out = (float*)d_out;

    char* ws = (char*)d_ws;
    const size_t MB = 1u << 20;
    const size_t need = 8192 + 3 * MB + (MB / 2);
    if (ws_size < need) return;  // fail loudly (validation will catch)

    float* w    = (float*)(ws);                    // 512 f32
    float* btot = (float*)(ws + 2048);             // 512 f32
    float* bmid = (float*)(ws + 4096);             // 512 f32
    float* W1   = (float*)(ws + 8192);             // 512x512 f32
    float* M2   = (float*)(ws + 8192 + 1 * MB);    // 512x512 f32
    float* Mtot = (float*)(ws + 8192 + 2 * MB);    // 512x512 f32
    unsigned short* Bt = (unsigned short*)(ws + 8192 + 3 * MB);  // 512x512 bf16

    // 1) w = sup_coeffs . sup_W
    k_w<<<dim3(2), dim3(256), 0, stream>>>(sup_c, sup_W, w);
    // 2) W1 = entangle(in_W rows); bmid = entangle(in_b)
    k_entangle<<<dim3(512, 4), dim3(128), 0, stream>>>(in_W, ent_W, ent_s, W1);
    k_entangle<<<dim3(1, 4), dim3(128), 0, stream>>>(in_b, ent_W, ent_s, bmid);
    // 3) superposition + circuit layers (in place)
    k_quadops<<<dim3(256), dim3(256), 0, stream>>>(W1, w, cp, 512);
    k_quadops<<<dim3(1), dim3(256), 0, stream>>>(bmid, w, cp, 1);
    // 4) M2 = meas_ops @ out_W
    k_convT<<<dim3(8, 8), dim3(256), 0, stream>>>(out_W, Bt);
    k_gemm<<<dim3(4, 4), dim3(256), 0, stream>>>(meas, Bt, M2, nullptr);
    // 5) Mtot = W1 @ M2
    k_convT<<<dim3(8, 8), dim3(256), 0, stream>>>(M2, Bt);
    k_gemm<<<dim3(4, 4), dim3(256), 0, stream>>>(W1, Bt, Mtot, nullptr);
    // 6) btot = bmid @ M2 + out_b
    k_bias<<<dim3(2), dim3(256), 0, stream>>>(bmid, M2, out_b, btot);
    // 7) out = x @ Mtot + btot
    k_convT<<<dim3(8, 8), dim3(256), 0, stream>>>(Mtot, Bt);
    k_gemm<<<dim3(128, 4), dim3(256), 0, stream>>>(x, Bt, out, btot);
}

// Round 2
// 89.895 us; speedup vs baseline: 1.3169x; 1.3169x over previous
//
#include <hip/hip_runtime.h>
#include <hip/hip_bf16.h>

// out = x @ Mtot + btot, with Mtot = in_W @ L @ meas @ out_W built once.
// L (entangle + superposition + 3 circuit layers) is linear along hidden dim,
// applied directly to rows of in_W / in_b in k_prep.

typedef float  fvec4 __attribute__((ext_vector_type(4)));
typedef float  f32x4 __attribute__((ext_vector_type(4)));
typedef short  short8 __attribute__((ext_vector_type(8)));
typedef unsigned short us8 __attribute__((ext_vector_type(8)));
typedef unsigned short us4 __attribute__((ext_vector_type(4)));

#define H 512
#define NL 3
#define LDT 72   // LDS row stride (bf16 elems); 144 B -> conflict-free b128 pattern

__device__ __forceinline__ unsigned short f2bf(float f) {
    return __bfloat16_as_ushort(__float2bfloat16(f));
}

// ---------------------------------------------------------------------------
// k_prep: per row r of [in_W ; in_b], apply entangle -> superposition -> layers.
// One block (512 thr) per row. Row 512 is in_b -> bmid.
// ---------------------------------------------------------------------------
__global__ __launch_bounds__(512) void k_prep(const float* __restrict__ in_W,
                                              const float* __restrict__ in_b,
                                              const float* __restrict__ entW,
                                              const float* __restrict__ strength,
                                              const float* __restrict__ supW,
                                              const float* __restrict__ coeffs,
                                              const float* __restrict__ cp,
                                              float* __restrict__ W1f,
                                              float* __restrict__ bmid) {
    __shared__ float sseg[H];
    __shared__ float sval[H];
    __shared__ float sw[H];
    const int r = blockIdx.x;
    const int tid = threadIdx.x;
    const float* src = (r < H) ? (in_W + (size_t)r * H) : in_b;
    float* dst = (r < H) ? (W1f + (size_t)r * H) : bmid;

    // phase 1: load row + per-column superposition weight
    sseg[tid] = src[tid];
    float wacc = 0.f;
#pragma unroll
    for (int s = 0; s < 8; ++s) wacc += coeffs[s] * supW[s * H + tid];
    sw[tid] = wacc;
    __syncthreads();

    // phase 2: entangle. p = pair, j = col within pair; CNOT permutes cols 2<->3.
    const int p = tid >> 7, j = tid & 127;
    const int jsrc = (j & 2) ? (j ^ 1) : j;
    const float* wcol = entW + p * (128 * 128) + jsrc;
    const float* seg = sseg + p * 128;
    float acc = 0.f;
#pragma unroll 8
    for (int i = 0; i < 128; ++i) acc += seg[i] * wcol[i * 128];
    acc *= strength[p];
    __syncthreads();
    sval[tid] = acc;
    __syncthreads();

    // phase 3: quad-local gates (each thread redundantly does its quad)
    const int q4 = tid & ~3;
    float v0 = sval[q4], v1 = sval[q4 + 1], v2 = sval[q4 + 2], v3 = sval[q4 + 3];
    const float is2 = 0.70710678118654752440f;
    float t0, t1, t2, t3;
    t0 = (v0 + v1) * is2; t1 = (v0 - v1) * is2;
    t2 = (v2 + v3) * is2; t3 = (v2 - v3) * is2;
    v0 = t0 * sw[q4]; v1 = t1 * sw[q4 + 1]; v2 = t2 * sw[q4 + 2]; v3 = t3 * sw[q4 + 3];
    const int qb = tid >> 6;
#pragma unroll
    for (int l = 0; l < NL; ++l) {
        float px = cp[l * 24 + qb * 3 + 0];
        float pz = cp[l * 24 + qb * 3 + 2];
        t0 = (v0 + v1) * is2; t1 = (v0 - v1) * is2;
        t2 = (v2 + v3) * is2; t3 = (v2 - v3) * is2;
        v0 = t0; v1 = t1; v2 = t2; v3 = t3;
        t0 = v0 + px * v1; t1 = v1 + px * v0;
        t2 = v2 + px * v3; t3 = v3 + px * v2;
        v0 = t0; v1 = t1; v2 = t2; v3 = t3;
        v0 *= (1.f + pz); v1 *= (1.f - pz);
        v2 *= (1.f + pz); v3 *= (1.f - pz);
        t0 = v2; v2 = v3; v3 = t0;   // CNOT
    }
    const int pos = tid & 3;
    float res = (pos == 0) ? v0 : (pos == 1) ? v1 : (pos == 2) ? v2 : v3;
    dst[tid] = res;
}

// ---------------------------------------------------------------------------
// GEMM: C[M x 512] = A[M x 512](f32) @ B[512 x 512] (+bias)
// BMODE 0: B = bf16 transposed [n][k];  BMODE 1: B = f32 row-major [k][n]
// CMODE 0: C = f32 row-major + bias;    CMODE 1: C = bf16 transposed [n][m]
// 128x128 tile, BK=64, 4 waves (2x2), mfma 16x16x32 bf16.
// ---------------------------------------------------------------------------
template <int BMODE, int CMODE>
__global__ __launch_bounds__(256) void k_gemm(const float* __restrict__ A,
                                              const void* __restrict__ Bp,
                                              void* __restrict__ Cp,
                                              const float* __restrict__ bias) {
    __shared__ __align__(16) unsigned short As[128 * LDT];
    __shared__ __align__(16) unsigned short Bs[128 * LDT];
    const int tid = threadIdx.x;
    const int bm = blockIdx.x * 128, bn = blockIdx.y * 128;
    const int lane = tid & 63, wid = tid >> 6;
    const int wm = wid >> 1, wn = wid & 1;
    const int ro = lane & 15, ko8 = (lane >> 4) * 8;

    f32x4 acc[4][4];
#pragma unroll
    for (int i = 0; i < 4; ++i)
#pragma unroll
        for (int j = 0; j < 4; ++j) acc[i][j] = (f32x4)0.f;

    for (int kt = 0; kt < H; kt += 64) {
        __syncthreads();
        // stage A: 128 rows x 64 k, f32 -> bf16. 1024 chunks of 8 elems.
#pragma unroll
        for (int i = 0; i < 4; ++i) {
            int c = i * 256 + tid;
            int rr = c >> 3, kc = (c & 7) * 8;
            const float* s = A + (size_t)(bm + rr) * H + kt + kc;
            fvec4 a0 = *reinterpret_cast<const fvec4*>(s);
            fvec4 a1 = *reinterpret_cast<const fvec4*>(s + 4);
            us8 hv;
            hv[0] = f2bf(a0.x); hv[1] = f2bf(a0.y); hv[2] = f2bf(a0.z); hv[3] = f2bf(a0.w);
            hv[4] = f2bf(a1.x); hv[5] = f2bf(a1.y); hv[6] = f2bf(a1.z); hv[7] = f2bf(a1.w);
            *reinterpret_cast<us8*>(&As[rr * LDT + kc]) = hv;
        }
        if (BMODE == 0) {
            const unsigned short* Bt = (const unsigned short*)Bp;
#pragma unroll
            for (int i = 0; i < 4; ++i) {
                int c = i * 256 + tid;
                int rr = c >> 3, kc = (c & 7) * 8;
                us8 v = *reinterpret_cast<const us8*>(Bt + (size_t)(bn + rr) * H + kt + kc);
                *reinterpret_cast<us8*>(&Bs[rr * LDT + kc]) = v;
            }
        } else {
            const float* B = (const float*)Bp;
#pragma unroll
            for (int i = 0; i < 8; ++i) {
                int c = i * 256 + tid;
                int k = c >> 5, n0 = (c & 31) * 4;
                fvec4 v = *reinterpret_cast<const fvec4*>(B + (size_t)(kt + k) * H + bn + n0);
                Bs[(n0 + 0) * LDT + k] = f2bf(v.x);
                Bs[(n0 + 1) * LDT + k] = f2bf(v.y);
                Bs[(n0 + 2) * LDT + k] = f2bf(v.z);
                Bs[(n0 + 3) * LDT + k] = f2bf(v.w);
            }
        }
        __syncthreads();

#pragma unroll
        for (int kk = 0; kk < 2; ++kk) {
            short8 af[4], bf[4];
#pragma unroll
            for (int am = 0; am < 4; ++am)
                af[am] = *reinterpret_cast<const short8*>(&As[(wm * 64 + am * 16 + ro) * LDT + kk * 32 + ko8]);
#pragma unroll
            for (int bj = 0; bj < 4; ++bj)
                bf[bj] = *reinterpret_cast<const short8*>(&Bs[(wn * 64 + bj * 16 + ro) * LDT + kk * 32 + ko8]);
#pragma unroll
            for (int am = 0; am < 4; ++am)
#pragma unroll
                for (int bj = 0; bj < 4; ++bj)
                    acc[am][bj] = __builtin_amdgcn_mfma_f32_16x16x32_bf16(af[am], bf[bj], acc[am][bj], 0, 0, 0);
        }
    }

    // epilogue: C/D mapping col=lane&15, row=(lane>>4)*4+j
    const int crow = (lane >> 4) * 4;
    const int ccol = lane & 15;
#pragma unroll
    for (int am = 0; am < 4; ++am) {
#pragma unroll
        for (int bj = 0; bj < 4; ++bj) {
            const int gcol = bn + wn * 64 + bj * 16 + ccol;
            const int grow = bm + wm * 64 + am * 16 + crow;
            if (CMODE == 0) {
                float* C = (float*)Cp;
                const float bv = bias ? bias[gcol] : 0.f;
#pragma unroll
                for (int j = 0; j < 4; ++j)
                    C[(size_t)(grow + j) * H + gcol] = acc[am][bj][j] + bv;
            } else {
                unsigned short* Ct = (unsigned short*)Cp;
                us4 hv;
                hv[0] = f2bf(acc[am][bj][0]); hv[1] = f2bf(acc[am][bj][1]);
                hv[2] = f2bf(acc[am][bj][2]); hv[3] = f2bf(acc[am][bj][3]);
                *reinterpret_cast<us4*>(Ct + (size_t)gcol * H + grow) = hv;
            }
        }
    }
}

// btot[o] = sum_h bmid[h] * M2t[o][h] + out_b[o]   (M2t is bf16 transposed)
__global__ void k_bias(const float* __restrict__ bmid, const unsigned short* __restrict__ M2t,
                       const float* __restrict__ outb, float* __restrict__ btot) {
    int o = blockIdx.x * blockDim.x + threadIdx.x;
    if (o >= H) return;
    float acc = outb[o];
    const unsigned short* row = M2t + (size_t)o * H;
#pragma unroll 8
    for (int h = 0; h < H; ++h) {
        unsigned int u = (unsigned int)row[h] << 16;
        acc += bmid[h] * __uint_as_float(u);
    }
    btot[o] = acc;
}

extern "C" void kernel_launch(void* const* d_in, const int* in_sizes, int n_in,
                              void* d_out, int out_size, void* d_ws, size_t ws_size,
                              hipStream_t stream) {
    const float* x      = (const float*)d_in[0];   // (8,2048,512)
    const float* in_W   = (const float*)d_in[1];   // (512,512)
    const float* in_b   = (const float*)d_in[2];   // (512,)
    const float* ent_W  = (const float*)d_in[3];   // (4,128,128)
    const float* ent_s  = (const float*)d_in[4];   // (4,)
    const float* sup_W  = (const float*)d_in[5];   // (8,512)
    const float* sup_c  = (const float*)d_in[6];   // (8,)
    const float* cp     = (const float*)d_in[7];   // (3,8,3)
    const float* meas   = (const float*)d_in[8];   // (512,512)
    const float* out_W  = (const float*)d_in[9];   // (512,512)
    const float* out_b  = (const float*)d_in[10];  // (512,)
    float* out = (float*)d_out;

    char* ws = (char*)d_ws;
    const size_t MB = 1u << 20;
    const size_t need = 4096 * 4 + MB + 2 * (MB / 2);
    if (ws_size < need) return;

    float* bmid = (float*)(ws);                      // 512 f32
    float* btot = (float*)(ws + 4096);               // 512 f32
    float* W1f  = (float*)(ws + 16384);              // 512x512 f32
    unsigned short* M2t   = (unsigned short*)(ws + 16384 + MB);            // bf16 T
    unsigned short* MtotT = (unsigned short*)(ws + 16384 + MB + MB / 2);   // bf16 T

    // 1) middle map applied to rows of in_W (and in_b)
    k_prep<<<dim3(513), dim3(512), 0, stream>>>(in_W, in_b, ent_W, ent_s, sup_W, sup_c, cp, W1f, bmid);
    // 2) M2t = (meas @ out_W)^T bf16
    k_gemm<1, 1><<<dim3(4, 4), dim3(256), 0, stream>>>(meas, out_W, M2t, nullptr);
    // 3) btot = bmid @ M2 + out_b
    k_bias<<<dim3(2), dim3(256), 0, stream>>>(bmid, M2t, out_b, btot);
    // 4) MtotT = (W1 @ M2)^T bf16
    k_gemm<0, 1><<<dim3(4, 4), dim3(256), 0, stream>>>(W1f, M2t, MtotT, nullptr);
    // 5) out = x @ Mtot + btot
    k_gemm<0, 0><<<dim3(128, 4), dim3(256), 0, stream>>>(x, MtotT, out, btot);
}

// Round 3
// 61.436 us; speedup vs baseline: 1.9269x; 1.4632x over previous
//
#include <hip/hip_runtime.h>
#include <hip/hip_bf16.h>

// out = x @ Mtot + btot;  Mtot = in_W @ L @ meas @ out_W  (L = middle linear map)
// K1: prep rows of [in_W;in_b] through L  (513 blocks)  ||  M2t = (meas@out_W)^T  (16 blocks)
// K2: MtotT = (W1 @ M2)^T  (16 blocks)  ||  btot = bmid@M2 + out_b  (1 block)
// K3: out = x @ Mtot + btot   (BM=64 x BN=512, double-buffered, swizzled LDS)

typedef float  fvec4 __attribute__((ext_vector_type(4)));
typedef float  f32x4 __attribute__((ext_vector_type(4)));
typedef short  short8 __attribute__((ext_vector_type(8)));
typedef unsigned short us8 __attribute__((ext_vector_type(8)));
typedef unsigned short us4 __attribute__((ext_vector_type(4)));

#define H 512
#define NL 3
#define LDT 72   // padded LDS stride (small gemms)

__device__ __forceinline__ unsigned short f2bf(float f) {
    return __bfloat16_as_ushort(__float2bfloat16(f));
}
__device__ __forceinline__ float bf2f(unsigned short u) {
    return __uint_as_float((unsigned int)u << 16);
}
__device__ __forceinline__ void gll16(const void* g, void* l) {
    __builtin_amdgcn_global_load_lds((const __attribute__((address_space(1))) void*)g,
                                     (__attribute__((address_space(3))) void*)l, 16, 0, 0);
}

// ---------------------------------------------------------------------------
// prep path: one block per row of [in_W ; in_b], apply entangle->superpos->layers
// ---------------------------------------------------------------------------
__device__ void prep_row(int r, const float* __restrict__ in_W, const float* __restrict__ in_b,
                         const float* __restrict__ entW, const float* __restrict__ strength,
                         const float* __restrict__ supW, const float* __restrict__ coeffs,
                         const float* __restrict__ cp, float* __restrict__ W1f,
                         float* __restrict__ bmid, char* smem) {
    float* sseg = (float*)smem;
    float* sval = sseg + H;
    float* sw   = sval + H;
    const int tid = threadIdx.x;
    const float* src = (r < H) ? (in_W + (size_t)r * H) : in_b;
    float* dst = (r < H) ? (W1f + (size_t)r * H) : bmid;

    sseg[tid] = src[tid];
    float wacc = 0.f;
#pragma unroll
    for (int s = 0; s < 8; ++s) wacc += coeffs[s] * supW[s * H + tid];
    sw[tid] = wacc;
    __syncthreads();

    const int p = tid >> 7, j = tid & 127;
    const int jsrc = (j & 2) ? (j ^ 1) : j;
    const float* wcol = entW + p * (128 * 128) + jsrc;
    const float* seg = sseg + p * 128;
    float acc = 0.f;
#pragma unroll 8
    for (int i = 0; i < 128; ++i) acc += seg[i] * wcol[i * 128];
    acc *= strength[p];
    __syncthreads();
    sval[tid] = acc;
    __syncthreads();

    const int q4 = tid & ~3;
    float v0 = sval[q4], v1 = sval[q4 + 1], v2 = sval[q4 + 2], v3 = sval[q4 + 3];
    const float is2 = 0.70710678118654752440f;
    float t0, t1, t2, t3;
    t0 = (v0 + v1) * is2; t1 = (v0 - v1) * is2;
    t2 = (v2 + v3) * is2; t3 = (v2 - v3) * is2;
    v0 = t0 * sw[q4]; v1 = t1 * sw[q4 + 1]; v2 = t2 * sw[q4 + 2]; v3 = t3 * sw[q4 + 3];
    const int qb = tid >> 6;
#pragma unroll
    for (int l = 0; l < NL; ++l) {
        float px = cp[l * 24 + qb * 3 + 0];
        float pz = cp[l * 24 + qb * 3 + 2];
        t0 = (v0 + v1) * is2; t1 = (v0 - v1) * is2;
        t2 = (v2 + v3) * is2; t3 = (v2 - v3) * is2;
        v0 = t0; v1 = t1; v2 = t2; v3 = t3;
        t0 = v0 + px * v1; t1 = v1 + px * v0;
        t2 = v2 + px * v3; t3 = v3 + px * v2;
        v0 = t0; v1 = t1; v2 = t2; v3 = t3;
        v0 *= (1.f + pz); v1 *= (1.f - pz);
        v2 *= (1.f + pz); v3 *= (1.f - pz);
        t0 = v2; v2 = v3; v3 = t0;
    }
    const int pos = tid & 3;
    float res = (pos == 0) ? v0 : (pos == 1) ? v1 : (pos == 2) ? v2 : v3;
    dst[tid] = res;
}

// ---------------------------------------------------------------------------
// small 128x128-tile GEMM (512 thr, 8 waves 2x4), C written bf16-transposed.
// BMODE 0: B = bf16 [n][k];  BMODE 1: B = f32 row-major [k][n]
// ---------------------------------------------------------------------------
template <int BMODE>
__device__ void gemm128(const float* __restrict__ Ag, const void* __restrict__ Bg,
                        unsigned short* __restrict__ Ct, int bm, int bn, char* smem) {
    unsigned short* As = (unsigned short*)smem;
    unsigned short* Bs = As + 128 * LDT;
    const int tid = threadIdx.x;
    const int lane = tid & 63, wid = tid >> 6;
    const int wm = wid >> 2, wn = wid & 3;
    const int ro = lane & 15, ko8 = (lane >> 4) * 8;

    f32x4 acc[4][2];
#pragma unroll
    for (int i = 0; i < 4; ++i)
#pragma unroll
        for (int j = 0; j < 2; ++j) acc[i][j] = (f32x4)0.f;

    for (int kt = 0; kt < H; kt += 64) {
        __syncthreads();
#pragma unroll
        for (int i = 0; i < 2; ++i) {                 // stage A (f32->bf16)
            int c = i * 512 + tid;
            int rr = c >> 3, kc = (c & 7) * 8;
            const float* s = Ag + (size_t)(bm + rr) * H + kt + kc;
            fvec4 a0 = *(const fvec4*)s, a1 = *(const fvec4*)(s + 4);
            us8 hv;
            hv[0] = f2bf(a0.x); hv[1] = f2bf(a0.y); hv[2] = f2bf(a0.z); hv[3] = f2bf(a0.w);
            hv[4] = f2bf(a1.x); hv[5] = f2bf(a1.y); hv[6] = f2bf(a1.z); hv[7] = f2bf(a1.w);
            *(us8*)&As[rr * LDT + kc] = hv;
        }
        if (BMODE == 0) {
            const unsigned short* Bt = (const unsigned short*)Bg;
#pragma unroll
            for (int i = 0; i < 2; ++i) {
                int c = i * 512 + tid;
                int rr = c >> 3, kc = (c & 7) * 8;
                *(us8*)&Bs[rr * LDT + kc] = *(const us8*)(Bt + (size_t)(bn + rr) * H + kt + kc);
            }
        } else {
            const float* B = (const float*)Bg;
#pragma unroll
            for (int i = 0; i < 4; ++i) {             // thread: (n, 4 k's) -> b64 write
                int c = i * 512 + tid;
                int n = c & 127, k0 = (c >> 7) * 4;
                us4 hv;
#pragma unroll
                for (int j = 0; j < 4; ++j)
                    hv[j] = f2bf(B[(size_t)(kt + k0 + j) * H + bn + n]);
                *(us4*)&Bs[n * LDT + k0] = hv;
            }
        }
        __syncthreads();

#pragma unroll
        for (int kk = 0; kk < 2; ++kk) {
            short8 af[4], bfr[2];
#pragma unroll
            for (int am = 0; am < 4; ++am)
                af[am] = *(const short8*)&As[(wm * 64 + am * 16 + ro) * LDT + kk * 32 + ko8];
#pragma unroll
            for (int bj = 0; bj < 2; ++bj)
                bfr[bj] = *(const short8*)&Bs[(wn * 32 + bj * 16 + ro) * LDT + kk * 32 + ko8];
#pragma unroll
            for (int am = 0; am < 4; ++am)
#pragma unroll
                for (int bj = 0; bj < 2; ++bj)
                    acc[am][bj] = __builtin_amdgcn_mfma_f32_16x16x32_bf16(af[am], bfr[bj], acc[am][bj], 0, 0, 0);
        }
    }

    const int crow = (lane >> 4) * 4, ccol = lane & 15;
#pragma unroll
    for (int am = 0; am < 4; ++am)
#pragma unroll
        for (int bj = 0; bj < 2; ++bj) {
            int gcol = bn + wn * 32 + bj * 16 + ccol;
            int grow = bm + wm * 64 + am * 16 + crow;
            us4 hv;
            hv[0] = f2bf(acc[am][bj][0]); hv[1] = f2bf(acc[am][bj][1]);
            hv[2] = f2bf(acc[am][bj][2]); hv[3] = f2bf(acc[am][bj][3]);
            *(us4*)(Ct + (size_t)gcol * H + grow) = hv;
        }
}

// K1: blocks 0..512 prep, 513..528 gemm (meas @ out_W -> M2t)
__global__ __launch_bounds__(512) void k_setup(const float* __restrict__ in_W,
                                               const float* __restrict__ in_b,
                                               const float* __restrict__ entW,
                                               const float* __restrict__ strength,
                                               const float* __restrict__ supW,
                                               const float* __restrict__ coeffs,
                                               const float* __restrict__ cp,
                                               const float* __restrict__ meas,
                                               const float* __restrict__ outW,
                                               float* __restrict__ W1f,
                                               float* __restrict__ bmid,
                                               unsigned short* __restrict__ M2t) {
    __shared__ __align__(16) char smem[2 * 128 * LDT * 2];
    const int bx = blockIdx.x;
    if (bx < 513) {
        prep_row(bx, in_W, in_b, entW, strength, supW, coeffs, cp, W1f, bmid, smem);
    } else {
        const int g = bx - 513;
        gemm128<1>(meas, outW, M2t, (g >> 2) * 128, (g & 3) * 128, smem);
    }
}

// K2: blocks 0..15 gemm (W1 @ M2 -> MtotT), block 16 bias
__global__ __launch_bounds__(512) void k_mid(const float* __restrict__ W1f,
                                             const unsigned short* __restrict__ M2t,
                                             const float* __restrict__ bmid,
                                             const float* __restrict__ outb,
                                             unsigned short* __restrict__ MtotT,
                                             float* __restrict__ btot) {
    __shared__ __align__(16) char smem[2 * 128 * LDT * 2];
    const int bx = blockIdx.x;
    if (bx < 16) {
        gemm128<0>(W1f, M2t, MtotT, (bx >> 2) * 128, (bx & 3) * 128, smem);
    } else {
        const int o = threadIdx.x;
        float acc = outb[o];
        const us8* row = (const us8*)(M2t + (size_t)o * H);
#pragma unroll 8
        for (int h8 = 0; h8 < 64; ++h8) {
            us8 v = row[h8];
#pragma unroll
            for (int j = 0; j < 8; ++j) acc += bmid[h8 * 8 + j] * bf2f(v[j]);
        }
        btot[o] = acc;
    }
}

// ---------------------------------------------------------------------------
// K3: out[16384 x 512] = x @ Mtot + btot.  BM=64, BN=512 (x read once).
// Double-buffered swizzled LDS; B staged via global_load_lds (pre-swizzled src).
// ---------------------------------------------------------------------------
__global__ __launch_bounds__(512) void k_main(const float* __restrict__ A,
                                              const unsigned short* __restrict__ Bt,
                                              float* __restrict__ C,
                                              const float* __restrict__ bias) {
    __shared__ __align__(16) unsigned short As[2][64 * 64];    // 2 x 8 KB, swizzled
    __shared__ __align__(16) unsigned short Bs[2][512 * 64];   // 2 x 64 KB, swizzled
    const int tid = threadIdx.x;
    const int bm = blockIdx.x * 64;
    const int lane = tid & 63, wid = tid >> 6;
    const int ro = lane & 15, ko8 = (lane >> 4) * 8;

    // A staging: one us8 chunk per thread (64 rows x 8 chunks = 512)
    const int arr = tid >> 3, akc = (tid & 7) * 8;
    const float* aptr = A + (size_t)(bm + arr) * H + akc;
    const int awoff = ((arr * 128 + akc * 2) ^ ((arr & 7) << 4));   // byte offset

    // B staging via gll: issue i covers rows i*64 + (tid>>3); src col pre-swizzled
    const int brow = tid >> 3;
    const char* bbase = (const char*)Bt + (size_t)brow * 1024 +
                        (((tid & 7) * 16) ^ ((brow & 7) << 4));
    const int bdst = wid * 1024;   // + i*8192, wave-uniform LDS base

    f32x4 acc[4][4];
#pragma unroll
    for (int i = 0; i < 4; ++i)
#pragma unroll
        for (int j = 0; j < 4; ++j) acc[i][j] = (f32x4)0.f;

    // prologue: stage tile 0 into buf 0
    {
        fvec4 a0 = *(const fvec4*)aptr, a1 = *(const fvec4*)(aptr + 4);
#pragma unroll
        for (int i = 0; i < 8; ++i)
            gll16(bbase + (size_t)i * 65536, (char*)&Bs[0][0] + i * 8192 + bdst);
        us8 hv;
        hv[0] = f2bf(a0.x); hv[1] = f2bf(a0.y); hv[2] = f2bf(a0.z); hv[3] = f2bf(a0.w);
        hv[4] = f2bf(a1.x); hv[5] = f2bf(a1.y); hv[6] = f2bf(a1.z); hv[7] = f2bf(a1.w);
        *(us8*)((char*)&As[0][0] + awoff) = hv;
    }
    __syncthreads();

    for (int t = 0; t < 8; ++t) {
        const int buf = t & 1;
        fvec4 pa0, pa1;
        if (t < 7) {  // issue next tile's loads first (latency hides under MFMA)
            pa0 = *(const fvec4*)(aptr + (t + 1) * 64);
            pa1 = *(const fvec4*)(aptr + (t + 1) * 64 + 4);
#pragma unroll
            for (int i = 0; i < 8; ++i)
                gll16(bbase + (size_t)i * 65536 + (t + 1) * 128,
                      (char*)&Bs[buf ^ 1][0] + i * 8192 + bdst);
        }
        // compute current tile
#pragma unroll
        for (int kk = 0; kk < 2; ++kk) {
            short8 af[4], bfr[4];
#pragma unroll
            for (int am = 0; am < 4; ++am) {
                int row = am * 16 + ro;
                af[am] = *(const short8*)((const char*)&As[buf][0] +
                         ((row * 128 + (kk * 32 + ko8) * 2) ^ ((row & 7) << 4)));
            }
#pragma unroll
            for (int bj = 0; bj < 4; ++bj) {
                int row = wid * 64 + bj * 16 + ro;
                bfr[bj] = *(const short8*)((const char*)&Bs[buf][0] +
                          ((row * 128 + (kk * 32 + ko8) * 2) ^ ((row & 7) << 4)));
            }
#pragma unroll
            for (int am = 0; am < 4; ++am)
#pragma unroll
                for (int bj = 0; bj < 4; ++bj)
                    acc[am][bj] = __builtin_amdgcn_mfma_f32_16x16x32_bf16(af[am], bfr[bj], acc[am][bj], 0, 0, 0);
        }
        if (t < 7) {  // convert + write next A tile
            us8 hv;
            hv[0] = f2bf(pa0.x); hv[1] = f2bf(pa0.y); hv[2] = f2bf(pa0.z); hv[3] = f2bf(pa0.w);
            hv[4] = f2bf(pa1.x); hv[5] = f2bf(pa1.y); hv[6] = f2bf(pa1.z); hv[7] = f2bf(pa1.w);
            *(us8*)((char*)&As[buf ^ 1][0] + awoff) = hv;
        }
        __syncthreads();
    }

    // epilogue
    const int crow = (lane >> 4) * 4, ccol = lane & 15;
#pragma unroll
    for (int am = 0; am < 4; ++am)
#pragma unroll
        for (int bj = 0; bj < 4; ++bj) {
            const int gcol = wid * 64 + bj * 16 + ccol;
            const float bv = bias[gcol];
            const int grow = bm + am * 16 + crow;
#pragma unroll
            for (int j = 0; j < 4; ++j)
                C[(size_t)(grow + j) * H + gcol] = acc[am][bj][j] + bv;
        }
}

extern "C" void kernel_launch(void* const* d_in, const int* in_sizes, int n_in,
                              void* d_out, int out_size, void* d_ws, size_t ws_size,
                              hipStream_t stream) {
    const float* x      = (const float*)d_in[0];
    const float* in_W   = (const float*)d_in[1];
    const float* in_b   = (const float*)d_in[2];
    const float* ent_W  = (const float*)d_in[3];
    const float* ent_s  = (const float*)d_in[4];
    const float* sup_W  = (const float*)d_in[5];
    const float* sup_c  = (const float*)d_in[6];
    const float* cp     = (const float*)d_in[7];
    const float* meas   = (const float*)d_in[8];
    const float* out_W  = (const float*)d_in[9];
    const float* out_b  = (const float*)d_in[10];
    float* out = (float*)d_out;

    char* ws = (char*)d_ws;
    const size_t MB = 1u << 20;
    if (ws_size < 16384 + MB + MB) return;

    float* bmid = (float*)(ws);
    float* btot = (float*)(ws + 4096);
    float* W1f  = (float*)(ws + 16384);                                  // 1 MB
    unsigned short* M2t   = (unsigned short*)(ws + 16384 + MB);          // 0.5 MB
    unsigned short* MtotT = (unsigned short*)(ws + 16384 + MB + MB / 2); // 0.5 MB

    k_setup<<<dim3(529), dim3(512), 0, stream>>>(in_W, in_b, ent_W, ent_s, sup_W,
                                                 sup_c, cp, meas, out_W, W1f, bmid, M2t);
    k_mid<<<dim3(17), dim3(512), 0, stream>>>(W1f, M2t, bmid, out_b, MtotT, btot);
    k_main<<<dim3(256), dim3(512), 0, stream>>>(x, MtotT, out, btot);
}